// Round 1
// baseline (1038.297 us; speedup 1.0000x reference)
//
#include <hip/hip_runtime.h>
#include <hip/hip_bf16.h>

// ---------- Problem constants (fixed-shape problem) ----------
// x: (B=2, L=2048, D=2048) f32; A_log: (D, N=8); x_proj_w: (16, D);
// dt_proj_w: (D, D); out_proj_w: (DM=1024, D). Output: (B, L, DM) f32.
constexpr int Bsz = 2;
constexpr int L   = 2048;
constexpr int D   = 2048;
constexpr int Nst = 8;
constexpr int DM  = 1024;
constexpr int M   = Bsz * L;   // 4096 rows for all GEMMs

typedef __bf16 bf16x8 __attribute__((ext_vector_type(8)));
typedef float f32x4 __attribute__((ext_vector_type(4)));

// ---------- float -> bf16 cast (vectorized) ----------
__global__ void cvt_f32_bf16(const float* __restrict__ in, __bf16* __restrict__ out, int n4) {
    int i = blockIdx.x * blockDim.x + threadIdx.x;
    if (i >= n4) return;
    float4 v = reinterpret_cast<const float4*>(in)[i];
    union { __bf16 b[4]; ushort4 u; } cv;
    cv.b[0] = (__bf16)v.x; cv.b[1] = (__bf16)v.y; cv.b[2] = (__bf16)v.z; cv.b[3] = (__bf16)v.w;
    reinterpret_cast<ushort4*>(out)[i] = cv.u;
}

// ---------- x_dbl = x @ x_proj_w^T + x_proj_b  (f32 exact; one wave per row) ----------
__global__ __launch_bounds__(256) void xdbl_kernel(
    const float* __restrict__ x, const float* __restrict__ w,
    const float* __restrict__ bias, float* __restrict__ xdbl)
{
    const int lane = threadIdx.x & 63;
    const int row  = (blockIdx.x * blockDim.x + threadIdx.x) >> 6;  // one wave per row
    if (row >= M) return;
    const float* xr = x + (size_t)row * D;
    float acc[16];
#pragma unroll
    for (int j = 0; j < 16; ++j) acc[j] = 0.f;
    for (int k = lane * 4; k < D; k += 64 * 4) {
        float4 xv = *reinterpret_cast<const float4*>(&xr[k]);
#pragma unroll
        for (int j = 0; j < 16; ++j) {
            float4 wv = *reinterpret_cast<const float4*>(&w[j * D + k]);
            acc[j] += xv.x * wv.x + xv.y * wv.y + xv.z * wv.z + xv.w * wv.w;
        }
    }
#pragma unroll
    for (int j = 0; j < 16; ++j) {
        float v = acc[j];
#pragma unroll
        for (int off = 32; off > 0; off >>= 1) v += __shfl_down(v, off, 64);
        if (lane == 0) xdbl[(size_t)row * 16 + j] = v + bias[j];
    }
}

// ---------- async global->LDS 16B helper ----------
__device__ inline void async16(__bf16* lds, const __bf16* g) {
    __builtin_amdgcn_global_load_lds(
        (const __attribute__((address_space(1))) void*)g,
        (__attribute__((address_space(3))) void*)lds, 16, 0, 0);
}

// ---------- C[M,N] = A[M,K] @ Bw[N,K]^T + bias ; MODE 1: softplus epilogue ----------
// m97 structure: 128x128 tile, BK=32, 4 waves (2x2), global_load_lds width 16,
// mfma_f32_16x16x32_bf16, single-buffer two-barrier K loop.
template <int MODE>
__global__ __launch_bounds__(256) void gemm_bt(
    const __bf16* __restrict__ A, const __bf16* __restrict__ Bw,
    const float* __restrict__ bias, float* __restrict__ C,
    int N, int K)
{
    constexpr int BM = 128, BN = 128, BK = 32;
    __shared__ __attribute__((aligned(16))) __bf16 lA[BM * BK];
    __shared__ __attribute__((aligned(16))) __bf16 lB[BN * BK];

    const int tid  = threadIdx.x;
    const int lane = tid & 63;
    const int wid  = tid >> 6;
    const int wm   = wid >> 1, wn = wid & 1;      // 2x2 waves, 64x64 each
    const int rowBase = blockIdx.y * BM;
    const int colBase = blockIdx.x * BN;
    const int lrow = lane & 15;                   // fragment row (A) / col (B)
    const int kgrp = lane >> 4;                   // k-group 0..3 (8 elems each)

    f32x4 acc[4][4];
#pragma unroll
    for (int i = 0; i < 4; ++i)
#pragma unroll
        for (int j = 0; j < 4; ++j) acc[i][j] = f32x4{0.f, 0.f, 0.f, 0.f};

    // staging: thread tid covers LDS elems [tid*8, tid*8+8) = row tid/4, cols (tid&3)*8..+8
    const int sr = tid >> 2;
    const int sc = (tid & 3) * 8;
    const __bf16* gA0 = A  + (size_t)(rowBase + sr)      * K + sc;
    const __bf16* gA1 = A  + (size_t)(rowBase + sr + 64) * K + sc;
    const __bf16* gB0 = Bw + (size_t)(colBase + sr)      * K + sc;
    const __bf16* gB1 = Bw + (size_t)(colBase + sr + 64) * K + sc;
    __bf16* lA0p = &lA[tid * 8];
    __bf16* lA1p = &lA[2048 + tid * 8];
    __bf16* lB0p = &lB[tid * 8];
    __bf16* lB1p = &lB[2048 + tid * 8];

    for (int k0 = 0; k0 < K; k0 += BK) {
        async16(lA0p, gA0 + k0);
        async16(lA1p, gA1 + k0);
        async16(lB0p, gB0 + k0);
        async16(lB1p, gB1 + k0);
        __syncthreads();   // compiler drains vmcnt before barrier

        bf16x8 af[4], bfr[4];
#pragma unroll
        for (int m = 0; m < 4; ++m)
            af[m] = *reinterpret_cast<const bf16x8*>(&lA[(wm * 64 + m * 16 + lrow) * BK + kgrp * 8]);
#pragma unroll
        for (int n = 0; n < 4; ++n)
            bfr[n] = *reinterpret_cast<const bf16x8*>(&lB[(wn * 64 + n * 16 + lrow) * BK + kgrp * 8]);
#pragma unroll
        for (int m = 0; m < 4; ++m)
#pragma unroll
            for (int n = 0; n < 4; ++n)
                acc[m][n] = __builtin_amdgcn_mfma_f32_16x16x32_bf16(af[m], bfr[n], acc[m][n], 0, 0, 0);
        __syncthreads();
    }

    // epilogue: C/D layout col = lane&15, row = (lane>>4)*4 + reg  [m89/m91 verified]
#pragma unroll
    for (int m = 0; m < 4; ++m) {
        const int row = rowBase + wm * 64 + m * 16 + kgrp * 4;
#pragma unroll
        for (int n = 0; n < 4; ++n) {
            const int col = colBase + wn * 64 + n * 16 + lrow;
            const float bv = bias[col];
#pragma unroll
            for (int r = 0; r < 4; ++r) {
                float v = acc[m][n][r] + bv;
                if (MODE == 1) v = (v > 20.f) ? v : log1pf(expf(v));   // softplus
                C[(size_t)(row + r) * N + col] = v;
            }
        }
    }
}

// ---------- sequential selective scan ----------
// one thread per (b,d) channel; N=8 state in registers; B_t/C_t staged in LDS per 128-step chunk
__global__ __launch_bounds__(64) void scan_kernel(
    const float* __restrict__ dt, const float* __restrict__ x,
    const float* __restrict__ xdbl, const float* __restrict__ A_log,
    __bf16* __restrict__ y_bf)
{
    const int tid = threadIdx.x;
    const int b   = blockIdx.x / (D / 64);
    const int d   = (blockIdx.x % (D / 64)) * 64 + tid;

    float A[Nst];
#pragma unroll
    for (int n = 0; n < Nst; ++n) A[n] = -expf(A_log[(size_t)d * Nst + n]);
    float h[Nst];
#pragma unroll
    for (int n = 0; n < Nst; ++n) h[n] = 0.f;

    __shared__ __attribute__((aligned(16))) float sBC[128 * 16];
    const float* xdbl_b = xdbl + (size_t)b * L * 16;
    const float* dt_b   = dt   + (size_t)b * L * D + d;
    const float* x_b    = x    + (size_t)b * L * D + d;
    __bf16*      y_b    = y_bf + (size_t)b * L * D + d;

    for (int c = 0; c < L / 128; ++c) {
        __syncthreads();
        const float4* src = reinterpret_cast<const float4*>(xdbl_b + (size_t)c * 128 * 16);
#pragma unroll
        for (int i = 0; i < 8; ++i)
            reinterpret_cast<float4*>(sBC)[tid + i * 64] = src[tid + i * 64];
        __syncthreads();

        for (int t2 = 0; t2 < 128; ++t2) {
            const int t = c * 128 + t2;
            const float dtv = dt_b[(size_t)t * D];
            const float xv  = x_b[(size_t)t * D];
            const float dtx = dtv * xv;
            const float* bc = &sBC[t2 * 16];
            float y = 0.f;
#pragma unroll
            for (int n = 0; n < Nst; ++n) {
                const float dA = __expf(dtv * A[n]);        // dt*A <= 0, stable
                h[n] = dA * h[n] + dtx * bc[n];             // bc[0..7]  = B_t
                y = fmaf(h[n], bc[8 + n], y);               // bc[8..15] = C_t
            }
            y_b[(size_t)t * D] = (__bf16)y;
        }
    }
}

extern "C" void kernel_launch(void* const* d_in, const int* in_sizes, int n_in,
                              void* d_out, int out_size, void* d_ws, size_t ws_size,
                              hipStream_t stream) {
    const float* x     = (const float*)d_in[0];
    const float* A_log = (const float*)d_in[1];
    const float* xpw   = (const float*)d_in[2];
    const float* xpb   = (const float*)d_in[3];
    const float* dtw   = (const float*)d_in[4];
    const float* dtb   = (const float*)d_in[5];
    const float* ow    = (const float*)d_in[6];
    const float* ob    = (const float*)d_in[7];
    float* out = (float*)d_out;

    char* ws = (char*)d_ws;
    __bf16* x_bf   = (__bf16*)(ws);                 // M*D bf16      = 16,777,216 B
    __bf16* dtw_bf = (__bf16*)(ws + 16777216);      // D*D bf16      =  8,388,608 B
    __bf16* ow_bf  = (__bf16*)(ws + 25165824);      // DM*D bf16     =  4,194,304 B
    float*  xdbl   = (float* )(ws + 29360128);      // M*16 f32      =    262,144 B
    float*  dtbuf  = (float* )(ws + 29622272);      // M*D f32       = 33,554,432 B
    __bf16* y_bf   = (__bf16*)(ws + 63176704);      // M*D bf16      = 16,777,216 B
                                                    // total ~80 MB

    // 1) bf16 copies of GEMM operands
    cvt_f32_bf16<<<(M * D / 4 + 255) / 256, 256, 0, stream>>>(x, x_bf, M * D / 4);
    cvt_f32_bf16<<<(D * D / 4 + 255) / 256, 256, 0, stream>>>(dtw, dtw_bf, D * D / 4);
    cvt_f32_bf16<<<(DM * D / 4 + 255) / 256, 256, 0, stream>>>(ow, ow_bf, DM * D / 4);

    // 2) B_t / C_t gates (exact f32)
    xdbl_kernel<<<M / 4, 256, 0, stream>>>(x, xpw, xpb, xdbl);

    // 3) dt = softplus(x @ dtw^T + dtb)   [M=4096, N=2048, K=2048]
    gemm_bt<1><<<dim3(D / 128, M / 128), 256, 0, stream>>>(x_bf, dtw_bf, dtb, dtbuf, D, D);

    // 4) selective scan -> y (bf16)
    scan_kernel<<<Bsz * (D / 64), 64, 0, stream>>>(dtbuf, x, xdbl, A_log, y_bf);

    // 5) out = y @ ow^T + ob   [M=4096, N=1024, K=2048]
    gemm_bt<0><<<dim3(DM / 128, M / 128), 256, 0, stream>>>(y_bf, ow_bf, ob, out, DM, D);
}

// Round 2
// 225.875 us; speedup vs baseline: 4.5968x; 4.5968x over previous
//
#include <hip/hip_runtime.h>
#include <hip/hip_bf16.h>

// ---------- Problem constants (fixed-shape problem) ----------
constexpr int Bsz = 2;
constexpr int L   = 2048;
constexpr int D   = 2048;
constexpr int Nst = 8;
constexpr int DM  = 1024;
constexpr int M   = Bsz * L;   // 4096 rows for all GEMMs

constexpr int CH  = 64;        // scan chunks
constexpr int T   = L / CH;    // 32 steps per chunk
constexpr int BDN = Bsz * D * Nst;

typedef __bf16 bf16x8 __attribute__((ext_vector_type(8)));
typedef float f32x4 __attribute__((ext_vector_type(4)));

// ---------- float -> bf16 cast (vectorized) ----------
__global__ void cvt_f32_bf16(const float* __restrict__ in, __bf16* __restrict__ out, int n4) {
    int i = blockIdx.x * blockDim.x + threadIdx.x;
    if (i >= n4) return;
    float4 v = reinterpret_cast<const float4*>(in)[i];
    union { __bf16 b[4]; ushort4 u; } cv;
    cv.b[0] = (__bf16)v.x; cv.b[1] = (__bf16)v.y; cv.b[2] = (__bf16)v.z; cv.b[3] = (__bf16)v.w;
    reinterpret_cast<ushort4*>(out)[i] = cv.u;
}

// ---------- x_dbl = x @ x_proj_w^T + x_proj_b  (f32 exact; one wave per row) ----------
__global__ __launch_bounds__(256) void xdbl_kernel(
    const float* __restrict__ x, const float* __restrict__ w,
    const float* __restrict__ bias, float* __restrict__ xdbl)
{
    const int lane = threadIdx.x & 63;
    const int row  = (blockIdx.x * blockDim.x + threadIdx.x) >> 6;
    if (row >= M) return;
    const float* xr = x + (size_t)row * D;
    float acc[16];
#pragma unroll
    for (int j = 0; j < 16; ++j) acc[j] = 0.f;
    for (int k = lane * 4; k < D; k += 64 * 4) {
        float4 xv = *reinterpret_cast<const float4*>(&xr[k]);
#pragma unroll
        for (int j = 0; j < 16; ++j) {
            float4 wv = *reinterpret_cast<const float4*>(&w[j * D + k]);
            acc[j] += xv.x * wv.x + xv.y * wv.y + xv.z * wv.z + xv.w * wv.w;
        }
    }
#pragma unroll
    for (int j = 0; j < 16; ++j) {
        float v = acc[j];
#pragma unroll
        for (int off = 32; off > 0; off >>= 1) v += __shfl_down(v, off, 64);
        if (lane == 0) xdbl[(size_t)row * 16 + j] = v + bias[j];
    }
}

// ---------- async global->LDS 16B helper ----------
__device__ inline void async16(__bf16* lds, const __bf16* g) {
    __builtin_amdgcn_global_load_lds(
        (const __attribute__((address_space(1))) void*)g,
        (__attribute__((address_space(3))) void*)lds, 16, 0, 0);
}

// ---------- C[M,N] = A[M,K] @ Bw[N,K]^T + bias ; MODE 1: softplus epilogue ----------
template <int MODE>
__global__ __launch_bounds__(256) void gemm_bt(
    const __bf16* __restrict__ A, const __bf16* __restrict__ Bw,
    const float* __restrict__ bias, float* __restrict__ C,
    int N, int K)
{
    constexpr int BM = 128, BN = 128, BK = 32;
    __shared__ __attribute__((aligned(16))) __bf16 lA[BM * BK];
    __shared__ __attribute__((aligned(16))) __bf16 lB[BN * BK];

    const int tid  = threadIdx.x;
    const int lane = tid & 63;
    const int wid  = tid >> 6;
    const int wm   = wid >> 1, wn = wid & 1;
    const int rowBase = blockIdx.y * BM;
    const int colBase = blockIdx.x * BN;
    const int lrow = lane & 15;
    const int kgrp = lane >> 4;

    f32x4 acc[4][4];
#pragma unroll
    for (int i = 0; i < 4; ++i)
#pragma unroll
        for (int j = 0; j < 4; ++j) acc[i][j] = f32x4{0.f, 0.f, 0.f, 0.f};

    const int sr = tid >> 2;
    const int sc = (tid & 3) * 8;
    const __bf16* gA0 = A  + (size_t)(rowBase + sr)      * K + sc;
    const __bf16* gA1 = A  + (size_t)(rowBase + sr + 64) * K + sc;
    const __bf16* gB0 = Bw + (size_t)(colBase + sr)      * K + sc;
    const __bf16* gB1 = Bw + (size_t)(colBase + sr + 64) * K + sc;
    __bf16* lA0p = &lA[tid * 8];
    __bf16* lA1p = &lA[2048 + tid * 8];
    __bf16* lB0p = &lB[tid * 8];
    __bf16* lB1p = &lB[2048 + tid * 8];

    for (int k0 = 0; k0 < K; k0 += BK) {
        async16(lA0p, gA0 + k0);
        async16(lA1p, gA1 + k0);
        async16(lB0p, gB0 + k0);
        async16(lB1p, gB1 + k0);
        __syncthreads();

        bf16x8 af[4], bfr[4];
#pragma unroll
        for (int m = 0; m < 4; ++m)
            af[m] = *reinterpret_cast<const bf16x8*>(&lA[(wm * 64 + m * 16 + lrow) * BK + kgrp * 8]);
#pragma unroll
        for (int n = 0; n < 4; ++n)
            bfr[n] = *reinterpret_cast<const bf16x8*>(&lB[(wn * 64 + n * 16 + lrow) * BK + kgrp * 8]);
#pragma unroll
        for (int m = 0; m < 4; ++m)
#pragma unroll
            for (int n = 0; n < 4; ++n)
                acc[m][n] = __builtin_amdgcn_mfma_f32_16x16x32_bf16(af[m], bfr[n], acc[m][n], 0, 0, 0);
        __syncthreads();
    }

#pragma unroll
    for (int m = 0; m < 4; ++m) {
        const int row = rowBase + wm * 64 + m * 16 + kgrp * 4;
#pragma unroll
        for (int n = 0; n < 4; ++n) {
            const int col = colBase + wn * 64 + n * 16 + lrow;
            const float bv = bias[col];
#pragma unroll
            for (int r = 0; r < 4; ++r) {
                float v = acc[m][n][r] + bv;
                if (MODE == 1) v = (v > 20.f) ? v : log1pf(expf(v));
                C[(size_t)(row + r) * N + col] = v;
            }
        }
    }
}

// ================= chunk-parallel selective scan =================
// Phase 1: per (b, d-group, chunk): local scan from h=0 -> P (decay product), Hloc (final state)
__global__ __launch_bounds__(64) void scan_p1(
    const float* __restrict__ dt, const float* __restrict__ x,
    const float* __restrict__ xdbl, const float* __restrict__ A_log,
    float* __restrict__ P, float* __restrict__ Hloc)
{
    const int tid = threadIdx.x;
    int blk = blockIdx.x;
    const int c  = blk % CH;  blk /= CH;
    const int dg = blk % (D / 64);
    const int b  = blk / (D / 64);
    const int d  = dg * 64 + tid;

    float A[Nst], h[Nst], p[Nst];
#pragma unroll
    for (int n = 0; n < Nst; ++n) {
        A[n] = -expf(A_log[(size_t)d * Nst + n]);
        h[n] = 0.f; p[n] = 1.f;
    }

    // stage this chunk's B_t/C_t rows (T*16 floats = 2KB)
    __shared__ __attribute__((aligned(16))) float sBC[T * 16];
    const float4* src = reinterpret_cast<const float4*>(xdbl + ((size_t)b * L + c * T) * 16);
#pragma unroll
    for (int i = tid; i < T * 4; i += 64)
        reinterpret_cast<float4*>(sBC)[i] = src[i];
    __syncthreads();

    const float* dt_p = dt + ((size_t)b * L + c * T) * D + d;
    const float* x_p  = x  + ((size_t)b * L + c * T) * D + d;
#pragma unroll 4
    for (int t2 = 0; t2 < T; ++t2) {
        const float dtv = dt_p[(size_t)t2 * D];
        const float xv  = x_p[(size_t)t2 * D];
        const float dtx = dtv * xv;
        const float* bc = &sBC[t2 * 16];
#pragma unroll
        for (int n = 0; n < Nst; ++n) {
            const float dA = __expf(dtv * A[n]);
            p[n] *= dA;
            h[n] = dA * h[n] + dtx * bc[n];
        }
    }
    const size_t base = ((size_t)c * Bsz * D + (size_t)b * D + d) * Nst;
#pragma unroll
    for (int n = 0; n < Nst; ++n) { P[base + n] = p[n]; Hloc[base + n] = h[n]; }
}

// Phase 2: compose chunk summaries sequentially -> chunk-entry states
__global__ __launch_bounds__(256) void scan_p2(
    const float* __restrict__ P, const float* __restrict__ Hloc,
    float* __restrict__ Hstart)
{
    const int id = blockIdx.x * blockDim.x + threadIdx.x;   // (b,d,n) flattened
    if (id >= BDN) return;
    float h = 0.f;
    for (int c = 0; c < CH; ++c) {
        const size_t o = (size_t)c * BDN + id;
        Hstart[o] = h;
        h = P[o] * h + Hloc[o];
    }
}

// Phase 3: rerun each chunk from its exact entry state, emit y (bf16)
__global__ __launch_bounds__(64) void scan_p3(
    const float* __restrict__ dt, const float* __restrict__ x,
    const float* __restrict__ xdbl, const float* __restrict__ A_log,
    const float* __restrict__ Hstart, __bf16* __restrict__ y_bf)
{
    const int tid = threadIdx.x;
    int blk = blockIdx.x;
    const int c  = blk % CH;  blk /= CH;
    const int dg = blk % (D / 64);
    const int b  = blk / (D / 64);
    const int d  = dg * 64 + tid;

    float A[Nst], h[Nst];
    const size_t hbase = ((size_t)c * Bsz * D + (size_t)b * D + d) * Nst;
#pragma unroll
    for (int n = 0; n < Nst; ++n) {
        A[n] = -expf(A_log[(size_t)d * Nst + n]);
        h[n] = Hstart[hbase + n];
    }

    __shared__ __attribute__((aligned(16))) float sBC[T * 16];
    const float4* src = reinterpret_cast<const float4*>(xdbl + ((size_t)b * L + c * T) * 16);
#pragma unroll
    for (int i = tid; i < T * 4; i += 64)
        reinterpret_cast<float4*>(sBC)[i] = src[i];
    __syncthreads();

    const float* dt_p = dt + ((size_t)b * L + c * T) * D + d;
    const float* x_p  = x  + ((size_t)b * L + c * T) * D + d;
    __bf16*      y_p  = y_bf + ((size_t)b * L + c * T) * D + d;
#pragma unroll 4
    for (int t2 = 0; t2 < T; ++t2) {
        const float dtv = dt_p[(size_t)t2 * D];
        const float xv  = x_p[(size_t)t2 * D];
        const float dtx = dtv * xv;
        const float* bc = &sBC[t2 * 16];
        float y = 0.f;
#pragma unroll
        for (int n = 0; n < Nst; ++n) {
            const float dA = __expf(dtv * A[n]);
            h[n] = dA * h[n] + dtx * bc[n];
            y = fmaf(h[n], bc[8 + n], y);
        }
        y_p[(size_t)t2 * D] = (__bf16)y;
    }
}

extern "C" void kernel_launch(void* const* d_in, const int* in_sizes, int n_in,
                              void* d_out, int out_size, void* d_ws, size_t ws_size,
                              hipStream_t stream) {
    const float* x     = (const float*)d_in[0];
    const float* A_log = (const float*)d_in[1];
    const float* xpw   = (const float*)d_in[2];
    const float* xpb   = (const float*)d_in[3];
    const float* dtw   = (const float*)d_in[4];
    const float* dtb   = (const float*)d_in[5];
    const float* ow    = (const float*)d_in[6];
    const float* ob    = (const float*)d_in[7];
    float* out = (float*)d_out;

    char* ws = (char*)d_ws;
    __bf16* x_bf   = (__bf16*)(ws);                 // 16,777,216 B (dead after dt-GEMM)
    __bf16* dtw_bf = (__bf16*)(ws + 16777216);      //  8,388,608 B (dead after dt-GEMM)
    __bf16* ow_bf  = (__bf16*)(ws + 25165824);      //  4,194,304 B (live until out-GEMM)
    float*  xdbl   = (float* )(ws + 29360128);      //    262,144 B
    float*  dtbuf  = (float* )(ws + 29622272);      // 33,554,432 B
    __bf16* y_bf   = (__bf16*)(ws + 63176704);      // 16,777,216 B  -> 79,953,920 total
    // scan scratch overlays the dead bf16 operand copies:
    float*  P      = (float*)(ws);                  // 8,388,608 B (over x_bf lo)
    float*  Hloc   = (float*)(ws + 8388608);        // 8,388,608 B (over x_bf hi)
    float*  Hstart = (float*)(ws + 16777216);       // 8,388,608 B (over dtw_bf)

    // 1) bf16 copies of GEMM operands
    cvt_f32_bf16<<<(M * D / 4 + 255) / 256, 256, 0, stream>>>(x, x_bf, M * D / 4);
    cvt_f32_bf16<<<(D * D / 4 + 255) / 256, 256, 0, stream>>>(dtw, dtw_bf, D * D / 4);
    cvt_f32_bf16<<<(DM * D / 4 + 255) / 256, 256, 0, stream>>>(ow, ow_bf, DM * D / 4);

    // 2) B_t / C_t gates (exact f32)
    xdbl_kernel<<<M / 4, 256, 0, stream>>>(x, xpw, xpb, xdbl);

    // 3) dt = softplus(x @ dtw^T + dtb)
    gemm_bt<1><<<dim3(D / 128, M / 128), 256, 0, stream>>>(x_bf, dtw_bf, dtb, dtbuf, D, D);

    // 4) chunk-parallel selective scan -> y (bf16)
    const int scan_blocks = Bsz * (D / 64) * CH;    // 4096
    scan_p1<<<scan_blocks, 64, 0, stream>>>(dtbuf, x, xdbl, A_log, P, Hloc);
    scan_p2<<<(BDN + 255) / 256, 256, 0, stream>>>(P, Hloc, Hstart);
    scan_p3<<<scan_blocks, 64, 0, stream>>>(dtbuf, x, xdbl, A_log, Hstart, y_bf);

    // 5) out = y @ ow^T + ob
    gemm_bt<0><<<dim3(DM / 128, M / 128), 256, 0, stream>>>(y_bf, ow_bf, ob, out, DM, D);
}

// Round 3
// 185.754 us; speedup vs baseline: 5.5896x; 1.2160x over previous
//
#include <hip/hip_runtime.h>
#include <hip/hip_bf16.h>

// ---------- Problem constants (fixed-shape problem) ----------
constexpr int Bsz = 2;
constexpr int L   = 2048;
constexpr int D   = 2048;
constexpr int Nst = 8;
constexpr int DM  = 1024;
constexpr int M   = Bsz * L;   // 4096 rows for all GEMMs

constexpr int CH  = 64;        // scan chunks
constexpr int T   = L / CH;    // 32 steps per chunk
constexpr int BDN = Bsz * D * Nst;

typedef __bf16 bf16x8 __attribute__((ext_vector_type(8)));
typedef float f32x4 __attribute__((ext_vector_type(4)));

// ---------- float -> bf16 cast (for weights) ----------
__global__ void cvt_f32_bf16(const float* __restrict__ in, __bf16* __restrict__ out, int n4) {
    int i = blockIdx.x * blockDim.x + threadIdx.x;
    if (i >= n4) return;
    float4 v = reinterpret_cast<const float4*>(in)[i];
    union { __bf16 b[4]; ushort4 u; } cv;
    cv.b[0] = (__bf16)v.x; cv.b[1] = (__bf16)v.y; cv.b[2] = (__bf16)v.z; cv.b[3] = (__bf16)v.w;
    reinterpret_cast<ushort4*>(out)[i] = cv.u;
}

// ---------- x_dbl = x @ x_proj_w^T + b (f32 exact), fused x->bf16 emission ----------
// w (16x2048 f32 = 128 KB) staged once per block in LDS; block = 16 rows, 4 waves x 4 rows.
__global__ __launch_bounds__(256) void xdbl_kernel(
    const float* __restrict__ x, const float* __restrict__ w,
    const float* __restrict__ bias, float* __restrict__ xdbl,
    __bf16* __restrict__ x_bf)
{
    __shared__ float sw[16 * 2048];          // 128 KB (gfx950 allows up to 160K/WG)
    const int tid = threadIdx.x;
    for (int i = tid; i < 16 * 2048 / 4; i += 256)
        reinterpret_cast<float4*>(sw)[i] = reinterpret_cast<const float4*>(w)[i];
    __syncthreads();

    const int lane = tid & 63;
    const int wrow = tid >> 6;
    for (int rr = 0; rr < 4; ++rr) {
        const int row = blockIdx.x * 16 + wrow * 4 + rr;
        const float* xr = x + (size_t)row * D;
        __bf16* xb = x_bf + (size_t)row * D;
        float acc[16];
#pragma unroll
        for (int j = 0; j < 16; ++j) acc[j] = 0.f;
        for (int k = lane * 4; k < D; k += 256) {
            float4 xv = *reinterpret_cast<const float4*>(&xr[k]);
            union { __bf16 b[4]; ushort4 u; } cv;
            cv.b[0] = (__bf16)xv.x; cv.b[1] = (__bf16)xv.y;
            cv.b[2] = (__bf16)xv.z; cv.b[3] = (__bf16)xv.w;
            *reinterpret_cast<ushort4*>(&xb[k]) = cv.u;
#pragma unroll
            for (int j = 0; j < 16; ++j) {
                float4 wv = *reinterpret_cast<const float4*>(&sw[j * D + k]);
                acc[j] += xv.x * wv.x + xv.y * wv.y + xv.z * wv.z + xv.w * wv.w;
            }
        }
#pragma unroll
        for (int j = 0; j < 16; ++j) {
            float v = acc[j];
#pragma unroll
            for (int off = 32; off > 0; off >>= 1) v += __shfl_down(v, off, 64);
            if (lane == 0) xdbl[(size_t)row * 16 + j] = v + bias[j];
        }
    }
}

// ---------- async global->LDS 16B helper ----------
__device__ inline void async16(__bf16* lds, const __bf16* g) {
    __builtin_amdgcn_global_load_lds(
        (const __attribute__((address_space(1))) void*)g,
        (__attribute__((address_space(3))) void*)lds, 16, 0, 0);
}

// ---------- C[M,N] = A[M,K] @ Bw[N,K]^T + bias ; MODE 1: softplus epilogue ----------
// 128x128 tile, BK=64, double-buffered LDS (64 KB), prefetch depth 2,
// counted vmcnt(8) across raw barriers (T3/T4), T2 XOR swizzle (pre-swizzled
// global source + XOR'd ds_read addr), T5 setprio around MFMA cluster.
template <int MODE>
__global__ __launch_bounds__(256, 2) void gemm_bt(
    const __bf16* __restrict__ A, const __bf16* __restrict__ Bw,
    const float* __restrict__ bias, float* __restrict__ C,
    int N, int K)
{
    constexpr int BM = 128, BN = 128, BK = 64;
    const int NT = K / BK;                                   // 32 K-tiles
    __shared__ __attribute__((aligned(16))) __bf16 lds[2][2][BM * BK];  // [buf][A/B]

    const int tid  = threadIdx.x;
    const int lane = tid & 63;
    const int wid  = tid >> 6;
    const int wm   = wid >> 1, wn = wid & 1;                 // 2x2 waves, 64x64 each
    const int rowBase = blockIdx.y * BM;
    const int colBase = blockIdx.x * BN;
    const int lrow = lane & 15;
    const int kgrp = lane >> 4;

    // bias prefetch, then drain vmcnt so manual load counting below is exact
    float bv[4];
#pragma unroll
    for (int n = 0; n < 4; ++n) bv[n] = bias[colBase + wn * 64 + n * 16 + lrow];
    asm volatile("s_waitcnt vmcnt(0)" ::: "memory");

    // staging sources: LDS dest is linear (tid*16B per round); the 16B column each
    // thread fetches is pre-swizzled so that reads can XOR the same involution.
    const int trow = tid >> 3;                               // row within 32-row round
    const int scol = ((tid & 7) ^ (trow & 7)) * 8;           // swizzled element col
    const __bf16* gA[4]; const __bf16* gB[4];
#pragma unroll
    for (int ro = 0; ro < 4; ++ro) {
        gA[ro] = A  + (size_t)(rowBase + ro * 32 + trow) * K + scol;
        gB[ro] = Bw + (size_t)(colBase + ro * 32 + trow) * K + scol;
    }

    f32x4 acc[4][4];
#pragma unroll
    for (int i = 0; i < 4; ++i)
#pragma unroll
        for (int j = 0; j < 4; ++j) acc[i][j] = f32x4{0.f, 0.f, 0.f, 0.f};

    auto stage = [&](int kt, int bsel) {                     // 8 gload_lds / thread
        const int k0 = kt * BK;
#pragma unroll
        for (int ro = 0; ro < 4; ++ro) {
            async16(&lds[bsel][0][ro * 2048 + tid * 8], gA[ro] + k0);
            async16(&lds[bsel][1][ro * 2048 + tid * 8], gB[ro] + k0);
        }
    };

    stage(0, 0);           // 8 outstanding
    stage(1, 1);           // 16 outstanding

    for (int t = 0; t < NT; ++t) {
        // tile t's 8 loads retired; tile t+1's 8 stay in flight (never drain to 0)
        if (t == NT - 1) asm volatile("s_waitcnt vmcnt(0)" ::: "memory");
        else             asm volatile("s_waitcnt vmcnt(8)" ::: "memory");
        __builtin_amdgcn_s_barrier();                        // tile t resident for all waves

        const int cur = t & 1;
        bf16x8 af[4][2], bfr[4][2];
#pragma unroll
        for (int m = 0; m < 4; ++m) {
            const int row = wm * 64 + m * 16 + lrow;
#pragma unroll
            for (int kk = 0; kk < 2; ++kk) {
                const int slot = (kk * 4 + kgrp) ^ (lrow & 7);   // T2 read-side XOR
                af[m][kk] = *reinterpret_cast<const bf16x8*>(&lds[cur][0][row * 64 + slot * 8]);
            }
        }
#pragma unroll
        for (int n = 0; n < 4; ++n) {
            const int row = wn * 64 + n * 16 + lrow;
#pragma unroll
            for (int kk = 0; kk < 2; ++kk) {
                const int slot = (kk * 4 + kgrp) ^ (lrow & 7);
                bfr[n][kk] = *reinterpret_cast<const bf16x8*>(&lds[cur][1][row * 64 + slot * 8]);
            }
        }
        asm volatile("s_waitcnt lgkmcnt(0)" ::: "memory");   // my reads sampled
        __builtin_amdgcn_sched_barrier(0);                   // rule #18 fence
        __builtin_amdgcn_s_barrier();                        // ALL waves done reading buf[cur]

        if (t + 2 < NT) stage(t + 2, cur);                   // overwrite now safe; flies under MFMA

        __builtin_amdgcn_s_setprio(1);
#pragma unroll
        for (int kk = 0; kk < 2; ++kk)
#pragma unroll
            for (int m = 0; m < 4; ++m)
#pragma unroll
                for (int n = 0; n < 4; ++n)
                    acc[m][n] = __builtin_amdgcn_mfma_f32_16x16x32_bf16(af[m][kk], bfr[n][kk], acc[m][n], 0, 0, 0);
        __builtin_amdgcn_s_setprio(0);
    }

    // epilogue: C/D layout col = lane&15, row = (lane>>4)*4 + reg
#pragma unroll
    for (int m = 0; m < 4; ++m) {
        const int row = rowBase + wm * 64 + m * 16 + kgrp * 4;
#pragma unroll
        for (int n = 0; n < 4; ++n) {
            const int col = colBase + wn * 64 + n * 16 + lrow;
#pragma unroll
            for (int r = 0; r < 4; ++r) {
                float v = acc[m][n][r] + bv[n];
                if (MODE == 1) v = (v > 20.f) ? v : log1pf(expf(v));
                C[(size_t)(row + r) * N + col] = v;
            }
        }
    }
}

// ================= chunk-parallel selective scan =================
__global__ __launch_bounds__(64) void scan_p1(
    const float* __restrict__ dt, const float* __restrict__ x,
    const float* __restrict__ xdbl, const float* __restrict__ A_log,
    float* __restrict__ P, float* __restrict__ Hloc)
{
    const int tid = threadIdx.x;
    int blk = blockIdx.x;
    const int c  = blk % CH;  blk /= CH;
    const int dg = blk % (D / 64);
    const int b  = blk / (D / 64);
    const int d  = dg * 64 + tid;

    float A[Nst], h[Nst], p[Nst];
#pragma unroll
    for (int n = 0; n < Nst; ++n) {
        A[n] = -expf(A_log[(size_t)d * Nst + n]);
        h[n] = 0.f; p[n] = 1.f;
    }

    __shared__ __attribute__((aligned(16))) float sBC[T * 16];
    const float4* src = reinterpret_cast<const float4*>(xdbl + ((size_t)b * L + c * T) * 16);
#pragma unroll
    for (int i = tid; i < T * 4; i += 64)
        reinterpret_cast<float4*>(sBC)[i] = src[i];
    __syncthreads();

    const float* dt_p = dt + ((size_t)b * L + c * T) * D + d;
    const float* x_p  = x  + ((size_t)b * L + c * T) * D + d;
#pragma unroll 4
    for (int t2 = 0; t2 < T; ++t2) {
        const float dtv = dt_p[(size_t)t2 * D];
        const float xv  = x_p[(size_t)t2 * D];
        const float dtx = dtv * xv;
        const float* bc = &sBC[t2 * 16];
#pragma unroll
        for (int n = 0; n < Nst; ++n) {
            const float dA = __expf(dtv * A[n]);
            p[n] *= dA;
            h[n] = dA * h[n] + dtx * bc[n];
        }
    }
    const size_t base = ((size_t)c * Bsz * D + (size_t)b * D + d) * Nst;
#pragma unroll
    for (int n = 0; n < Nst; ++n) { P[base + n] = p[n]; Hloc[base + n] = h[n]; }
}

__global__ __launch_bounds__(256) void scan_p2(
    const float* __restrict__ P, const float* __restrict__ Hloc,
    float* __restrict__ Hstart)
{
    const int id = blockIdx.x * blockDim.x + threadIdx.x;
    if (id >= BDN) return;
    float h = 0.f;
    for (int c = 0; c < CH; ++c) {
        const size_t o = (size_t)c * BDN + id;
        Hstart[o] = h;
        h = P[o] * h + Hloc[o];
    }
}

__global__ __launch_bounds__(64) void scan_p3(
    const float* __restrict__ dt, const float* __restrict__ x,
    const float* __restrict__ xdbl, const float* __restrict__ A_log,
    const float* __restrict__ Hstart, __bf16* __restrict__ y_bf)
{
    const int tid = threadIdx.x;
    int blk = blockIdx.x;
    const int c  = blk % CH;  blk /= CH;
    const int dg = blk % (D / 64);
    const int b  = blk / (D / 64);
    const int d  = dg * 64 + tid;

    float A[Nst], h[Nst];
    const size_t hbase = ((size_t)c * Bsz * D + (size_t)b * D + d) * Nst;
#pragma unroll
    for (int n = 0; n < Nst; ++n) {
        A[n] = -expf(A_log[(size_t)d * Nst + n]);
        h[n] = Hstart[hbase + n];
    }

    __shared__ __attribute__((aligned(16))) float sBC[T * 16];
    const float4* src = reinterpret_cast<const float4*>(xdbl + ((size_t)b * L + c * T) * 16);
#pragma unroll
    for (int i = tid; i < T * 4; i += 64)
        reinterpret_cast<float4*>(sBC)[i] = src[i];
    __syncthreads();

    const float* dt_p = dt + ((size_t)b * L + c * T) * D + d;
    const float* x_p  = x  + ((size_t)b * L + c * T) * D + d;
    __bf16*      y_p  = y_bf + ((size_t)b * L + c * T) * D + d;
#pragma unroll 4
    for (int t2 = 0; t2 < T; ++t2) {
        const float dtv = dt_p[(size_t)t2 * D];
        const float xv  = x_p[(size_t)t2 * D];
        const float dtx = dtv * xv;
        const float* bc = &sBC[t2 * 16];
        float y = 0.f;
#pragma unroll
        for (int n = 0; n < Nst; ++n) {
            const float dA = __expf(dtv * A[n]);
            h[n] = dA * h[n] + dtx * bc[n];
            y = fmaf(h[n], bc[8 + n], y);
        }
        y_p[(size_t)t2 * D] = (__bf16)y;
    }
}

extern "C" void kernel_launch(void* const* d_in, const int* in_sizes, int n_in,
                              void* d_out, int out_size, void* d_ws, size_t ws_size,
                              hipStream_t stream) {
    const float* x     = (const float*)d_in[0];
    const float* A_log = (const float*)d_in[1];
    const float* xpw   = (const float*)d_in[2];
    const float* xpb   = (const float*)d_in[3];
    const float* dtw   = (const float*)d_in[4];
    const float* dtb   = (const float*)d_in[5];
    const float* ow    = (const float*)d_in[6];
    const float* ob    = (const float*)d_in[7];
    float* out = (float*)d_out;

    char* ws = (char*)d_ws;
    __bf16* x_bf   = (__bf16*)(ws);                 // 16,777,216 B (dead after dt-GEMM)
    __bf16* dtw_bf = (__bf16*)(ws + 16777216);      //  8,388,608 B (dead after dt-GEMM)
    __bf16* ow_bf  = (__bf16*)(ws + 25165824);      //  4,194,304 B (live until out-GEMM)
    float*  xdbl   = (float* )(ws + 29360128);      //    262,144 B
    float*  dtbuf  = (float* )(ws + 29622272);      // 33,554,432 B
    __bf16* y_bf   = (__bf16*)(ws + 63176704);      // 16,777,216 B
    // scan scratch overlays the dead bf16 operand copies:
    float*  P      = (float*)(ws);                  // over x_bf lo
    float*  Hloc   = (float*)(ws + 8388608);        // over x_bf hi
    float*  Hstart = (float*)(ws + 16777216);       // over dtw_bf

    // 1) bf16 weight copies
    cvt_f32_bf16<<<(D * D / 4 + 255) / 256, 256, 0, stream>>>(dtw, dtw_bf, D * D / 4);
    cvt_f32_bf16<<<(DM * D / 4 + 255) / 256, 256, 0, stream>>>(ow, ow_bf, DM * D / 4);

    // 2) B_t / C_t gates (exact f32) + fused x->bf16 emission
    xdbl_kernel<<<M / 16, 256, 0, stream>>>(x, xpw, xpb, xdbl, x_bf);

    // 3) dt = softplus(x @ dtw^T + dtb)
    gemm_bt<1><<<dim3(D / 128, M / 128), 256, 0, stream>>>(x_bf, dtw_bf, dtb, dtbuf, D, D);

    // 4) chunk-parallel selective scan -> y (bf16)
    const int scan_blocks = Bsz * (D / 64) * CH;    // 4096
    scan_p1<<<scan_blocks, 64, 0, stream>>>(dtbuf, x, xdbl, A_log, P, Hloc);
    scan_p2<<<(BDN + 255) / 256, 256, 0, stream>>>(P, Hloc, Hstart);
    scan_p3<<<scan_blocks, 64, 0, stream>>>(dtbuf, x, xdbl, A_log, Hstart, y_bf);

    // 5) out = y @ ow^T + ob
    gemm_bt<0><<<dim3(DM / 128, M / 128), 256, 0, stream>>>(y_bf, ow_bf, ob, out, DM, D);
}